// Round 9
// baseline (195.406 us; speedup 1.0000x reference)
//
#include <hip/hip_runtime.h>
#include <hip/hip_bf16.h>
#include <stdint.h>

// ---------------- MLA decoder self-attention, bf16-MFMA pipeline ----------------
// S=4096 E=1024 H=16 HD=64 ROPE=32 NOPE=32 QR=512 KVR=512, causal.
// R8: flash reverted to single-buffer (256,5) [R7 dbuf cost occupancy, no gain];
// KV-split deepened to chunk=8 (288 pairs, max 8 tiles/block) for tail-fill.

#define SLEN 4096
#define EDIM 1024
#define NH   16
#define NPAIR 288   // sum over qb of (qb>>3)+1

typedef __attribute__((ext_vector_type(8))) short short8;
typedef __attribute__((ext_vector_type(4))) float f32x4;

__device__ __forceinline__ ushort f2bf(float f) {
  __hip_bfloat16 h = __float2bfloat16(f);
  ushort u; __builtin_memcpy(&u, &h, 2); return u;
}
__device__ __forceinline__ float bf2f(ushort u) {
  uint32_t x = (uint32_t)u << 16;
  float f; __builtin_memcpy(&f, &x, 4); return f;
}
__device__ __forceinline__ uint32_t cvt_pk_bf16(float lo, float hi) {
  uint32_t r;
  asm("v_cvt_pk_bf16_f32 %0, %1, %2" : "=v"(r) : "v"(lo), "v"(hi));
  return r;
}

#define GLD_LDS16(g, l) __builtin_amdgcn_global_load_lds(                      \
    (const __attribute__((address_space(1))) uint32_t*)(g),                    \
    (__attribute__((address_space(3))) uint32_t*)(l), 16, 0, 0)

// ---------------- fused cast: 6 tensors f32 -> bf16, one launch ----------------
struct CastSeg { const float4* src; ushort* dst; int n4; };
struct CastArgs { CastSeg seg[6]; int total4; };
__global__ void cast_all(CastArgs a) {
  int i = blockIdx.x * blockDim.x + threadIdx.x;
  int stride = gridDim.x * blockDim.x;
  for (; i < a.total4; i += stride) {
    int idx = i, s = 0;
    while (idx >= a.seg[s].n4) { idx -= a.seg[s].n4; ++s; }
    float4 v = a.seg[s].src[idx];
    ushort4 o;
    o.x = f2bf(v.x); o.y = f2bf(v.y); o.z = f2bf(v.z); o.w = f2bf(v.w);
    *(ushort4*)(a.seg[s].dst + (size_t)idx * 4) = o;
  }
}

// ---------------- rope tables: cos/sin[s][16] ----------------
__global__ void rope_table(float* __restrict__ cosT, float* __restrict__ sinT) {
  int idx = blockIdx.x * blockDim.x + threadIdx.x;
  if (idx >= SLEN * 16) return;
  int s = idx >> 4, i = idx & 15;
  float inv = expf(-((float)(2 * i) / 32.0f) * logf(10000.0f));
  float ang = (float)s * inv;
  cosT[idx] = cosf(ang);
  sinT[idx] = sinf(ang);
}

// ---------------- GEMM body: C = A*B^T, 64x128 tile, 2-phase double-buffered ----------------
// ROPE epilogue: per-head rope on cols d>=32 via shfl_xor(v,1) partner + *SC (q_full fusion).
template <typename CT, bool ROPE>
__device__ __forceinline__ void gemm_body(
    ushort* As, ushort* Bs,
    const ushort* __restrict__ A, const ushort* __restrict__ B, CT* __restrict__ C,
    int M, int N, int K, int bx, int by,
    const float* __restrict__ cosT, const float* __restrict__ sinT) {
  const int tid = threadIdx.x;
  const int lane = tid & 63, wave = tid >> 6;
  const int bm = bx * 64, bn = by * 128;
  const int wm = (wave >> 1) * 32, wn = (wave & 1) * 64;

  f32x4 acc[2][4];
#pragma unroll
  for (int m = 0; m < 2; ++m)
#pragma unroll
    for (int n = 0; n < 4; ++n) acc[m][n] = (f32x4)0.0f;

  const int srow = lane >> 3;
  const int scb = (lane & 7) << 4;
  const int srcb = scb ^ ((srow & 7) << 4);

  auto stage = [&](int k0, int buf) {
#pragma unroll
    for (int c = 0; c < 2; ++c) {
      int r = wave * 16 + c * 8 + srow;
      const ushort* ga = A + (size_t)(bm + r) * K + k0 + (srcb >> 1);
      GLD_LDS16(ga, As + buf * 4096 + (wave * 16 + c * 8) * 64);
    }
#pragma unroll
    for (int c = 0; c < 4; ++c) {
      int r = wave * 32 + c * 8 + srow;
      int rb = bn + r; if (rb >= N) rb = N - 1;
      const ushort* gb = B + (size_t)rb * K + k0 + (srcb >> 1);
      GLD_LDS16(gb, Bs + buf * 8192 + (wave * 32 + c * 8) * 64);
    }
  };

  stage(0, 0);
  __syncthreads();
  int cur = 0;
  for (int k0 = 0; k0 < K; k0 += 64) {
    if (k0 + 64 < K) stage(k0 + 64, cur ^ 1);
    const char* Ab = (const char*)(As + cur * 4096);
    const char* Bb = (const char*)(Bs + cur * 8192);
#pragma unroll
    for (int kk = 0; kk < 2; ++kk) {
      short8 af[2], bf[4];
#pragma unroll
      for (int m = 0; m < 2; ++m) {
        int row = wm + m * 16 + (lane & 15);
        int cb = (kk * 64 + ((lane >> 4) << 4)) ^ ((row & 7) << 4);
        af[m] = *(const short8*)(Ab + row * 128 + cb);
      }
#pragma unroll
      for (int n = 0; n < 4; ++n) {
        int row = wn + n * 16 + (lane & 15);
        int cb = (kk * 64 + ((lane >> 4) << 4)) ^ ((row & 7) << 4);
        bf[n] = *(const short8*)(Bb + row * 128 + cb);
      }
#pragma unroll
      for (int m = 0; m < 2; ++m)
#pragma unroll
        for (int n = 0; n < 4; ++n)
          acc[m][n] = __builtin_amdgcn_mfma_f32_16x16x32_bf16(af[m], bf[n], acc[m][n], 0, 0, 0);
    }
    __syncthreads();
    cur ^= 1;
  }
  const float SCQ = 0.125f * 1.44269504089f;  // 1/sqrt(64) * log2(e)
#pragma unroll
  for (int m = 0; m < 2; ++m) {
    int gm = bm + wm + m * 16 + ((lane >> 4) << 2);
#pragma unroll
    for (int n = 0; n < 4; ++n) {
      int gn = bn + wn + n * 16 + (lane & 15);
      if (gn < N) {
#pragma unroll
        for (int r = 0; r < 4; ++r) {
          float v = acc[m][n][r];
          if constexpr (ROPE) {
            float partner = __shfl_xor(v, 1);  // col gn^1, same rows
            int d = gn & 63;
            if (d >= 32) {
              int s = gm + r, pidx = (d - 32) >> 1;
              float c = cosT[(s << 4) + pidx], sn = sinT[(s << 4) + pidx];
              v = (gn & 1) ? (partner * sn + v * c) : (v * c - partner * sn);
            }
            v *= SCQ;
          }
          if constexpr (__is_same(CT, ushort))
            C[(size_t)(gm + r) * N + gn] = f2bf(v);
          else
            C[(size_t)(gm + r) * N + gn] = v;
        }
      }
    }
  }
}

__global__ __launch_bounds__(256, 3) void gemm_f32k(
    const ushort* __restrict__ A, const ushort* __restrict__ B, float* __restrict__ C,
    int M, int N, int K) {
  __shared__ ushort As[2 * 64 * 64];
  __shared__ ushort Bs[2 * 128 * 64];
  gemm_body<float, false>(As, Bs, A, B, C, M, N, K, blockIdx.x, blockIdx.y, nullptr, nullptr);
}
__global__ __launch_bounds__(256, 3) void gemm_bf16k(
    const ushort* __restrict__ A, const ushort* __restrict__ B, ushort* __restrict__ C,
    int M, int N, int K) {
  __shared__ ushort As[2 * 64 * 64];
  __shared__ ushort Bs[2 * 128 * 64];
  gemm_body<ushort, false>(As, Bs, A, B, C, M, N, K, blockIdx.x, blockIdx.y, nullptr, nullptr);
}
// wqb (N=1024, y<8, rope+scale epilogue -> q_full) and wkvb (N=1536, y>=8)
__global__ __launch_bounds__(256, 3) void gemm_dual(
    const ushort* __restrict__ Aq, const ushort* __restrict__ Bq, ushort* __restrict__ Cq,
    const ushort* __restrict__ Ak, const ushort* __restrict__ Bk, ushort* __restrict__ Ck,
    const float* __restrict__ cosT, const float* __restrict__ sinT) {
  __shared__ ushort As[2 * 64 * 64];
  __shared__ ushort Bs[2 * 128 * 64];
  if (blockIdx.y < 8)
    gemm_body<ushort, true>(As, Bs, Aq, Bq, Cq, SLEN, 1024, 512, blockIdx.x, blockIdx.y, cosT, sinT);
  else
    gemm_body<ushort, false>(As, Bs, Ak, Bk, Ck, SLEN, 1536, 512, blockIdx.x, blockIdx.y - 8, nullptr, nullptr);
}

// ---------------- LayerNorm both halves (bf16 in): blocks 0..4095 q, 4096..8191 kv ----------------
__global__ __launch_bounds__(256) void ln_both(
    const ushort* __restrict__ qakv,
    const float* __restrict__ qa_w, const float* __restrict__ qa_b,
    const float* __restrict__ kva_w, const float* __restrict__ kva_b,
    ushort* __restrict__ qc, ushort* __restrict__ ckv,
    const float* __restrict__ cosT, const float* __restrict__ sinT,
    ushort* __restrict__ kpe) {
  const int row = blockIdx.x & 4095;
  const bool iskv = blockIdx.x >= 4096;
  const int tid = threadIdx.x;
  const ushort* px = qakv + (size_t)row * 1056 + (iskv ? 512 : 0);
  const float* w = iskv ? kva_w : qa_w;
  const float* b = iskv ? kva_b : qa_b;
  ushort* out = (iskv ? ckv : qc) + (size_t)row * 512;
  float x0 = bf2f(px[tid]), x1 = bf2f(px[tid + 256]);
  float s = x0 + x1, sq = x0 * x0 + x1 * x1;
#pragma unroll
  for (int off = 32; off; off >>= 1) {
    s += __shfl_down(s, off);
    sq += __shfl_down(sq, off);
  }
  __shared__ float redS[4], redQ[4];
  int wave = tid >> 6, lane = tid & 63;
  if (lane == 0) { redS[wave] = s; redQ[wave] = sq; }
  __syncthreads();
  float st = redS[0] + redS[1] + redS[2] + redS[3];
  float sqt = redQ[0] + redQ[1] + redQ[2] + redQ[3];
  float mean = st * (1.0f / 512.0f);
  float var = sqt * (1.0f / 512.0f) - mean * mean;
  float rstd = rsqrtf(var + 1e-5f);
  out[tid] = f2bf((x0 - mean) * rstd * w[tid] + b[tid]);
  out[tid + 256] = f2bf((x1 - mean) * rstd * w[tid + 256] + b[tid + 256]);
  if (iskv && tid < 32) {
    int p = tid >> 1;
    float xa = bf2f(px[512 + 2 * p]), xb = bf2f(px[512 + 2 * p + 1]);
    float c = cosT[(row << 4) + p], sn = sinT[(row << 4) + p];
    float v = (tid & 1) ? (xa * sn + xb * c) : (xa * c - xb * sn);
    kpe[(row << 5) + tid] = f2bf(v);
  }
}

// ---------------- pack k_full + V^T with k-permutation: vt[h][hd][perm(s)] ----------------
__global__ __launch_bounds__(256) void pack_kv2(
    const ushort* __restrict__ kvdec, const ushort* __restrict__ kpe,
    ushort* __restrict__ kf, ushort* __restrict__ vt) {
  __shared__ ushort T[64 * 65];
  const int tid = threadIdx.x;
  const int sb = blockIdx.x, h = blockIdx.y;
  const int s0 = sb * 64;
#pragma unroll 4
  for (int i = 0; i < 16; ++i) {
    int s_loc = i * 4 + (tid >> 6);
    int d = tid & 63;
    const ushort* base = kvdec + ((size_t)(s0 + s_loc) * 16 + h) * 96;
    T[d * 65 + s_loc] = base[32 + d];
    ushort kval = (d < 32) ? base[d] : kpe[((s0 + s_loc) << 5) + (d - 32)];
    kf[(size_t)(s0 + s_loc) * EDIM + h * 64 + d] = kval;
  }
  __syncthreads();
#pragma unroll 4
  for (int i = 0; i < 16; ++i) {
    int hd = i * 4 + (tid >> 6);
    int s_off = tid & 63;
    // pi(s): s = nf*16 + g*4 + r -> (nf&1)*32 + g*8 + (nf>>1)*4 + r (involution)
    int sp = ((s_off >> 4) & 1) * 32 + ((s_off >> 2) & 3) * 8 + ((s_off >> 5) & 1) * 4 + (s_off & 3);
    vt[(size_t)(h * 64 + hd) * SLEN + s0 + sp] = T[hd * 65 + s_off];
  }
}

// ---------------- flash attention, KV-split (chunk=8), swapped-QK, single-buffer ----------------
// Pair decode: group g = qb>>3 has g+1 chunks; cum(g) = 4g(g+1) pairs before group g.
__global__ __launch_bounds__(256, 5) void flash_part(
    const ushort* __restrict__ Qf, const ushort* __restrict__ Kf,
    const ushort* __restrict__ Vt, ushort* __restrict__ Opart, float* __restrict__ MLpart) {
  __shared__ ushort Klds[64 * 64];
  __shared__ ushort Vlds[64 * 64];
  const int tid = threadIdx.x, lane = tid & 63, wave = tid >> 6;
  const int p = NPAIR - 1 - blockIdx.x;   // 8-tile chunks dispatch first
  const int h = blockIdx.y;
  int g = 0, cum = 0;
  while (g < 7 && p >= cum + 8 * (g + 1)) { cum += 8 * (g + 1); ++g; }
  const int j = p - cum;
  const int qb = 8 * g + j / (g + 1);
  const int ck = j - (g + 1) * (j / (g + 1));
  const int q0 = qb * 64;
  const int t0 = ck * 8;
  const int t1 = min(t0 + 8, qb + 1);

  short8 aq[2];
  {
    const ushort* qrow =
        Qf + (((size_t)(q0 + wave * 16 + (lane & 15)) * 16 + h) << 6) + ((lane >> 4) << 3);
    aq[0] = *(const short8*)qrow;
    aq[1] = *(const short8*)(qrow + 32);
  }
  f32x4 oacc[4];
#pragma unroll
  for (int nf = 0; nf < 4; ++nf) oacc[nf] = (f32x4)0.0f;
  float lacc = 0.0f, mrun = -1e30f;

  const int strow = wave * 16 + (lane >> 3);
  const int srcb = ((lane & 7) << 4) ^ (((lane >> 3) & 7) << 4);

  for (int kb = t0; kb < t1; ++kb) {
#pragma unroll
    for (int c = 0; c < 2; ++c) {
      int r = strow + c * 8;
      const ushort* gk = Kf + (((size_t)(kb * 64 + r) * 16 + h) << 6) + (srcb >> 1);
      GLD_LDS16(gk, &Klds[(wave * 16 + c * 8) * 64]);
      const ushort* gv = Vt + (size_t)(h * 64 + r) * SLEN + kb * 64 + (srcb >> 1);
      GLD_LDS16(gv, &Vlds[(wave * 16 + c * 8) * 64]);
    }
    __syncthreads();

    // ---- S^T = K * Q^T : sfr[nf][r] = S[q=lane&15][k = nf*16 + (lane>>4)*4 + r] ----
    f32x4 sfr[4];
#pragma unroll
    for (int nf = 0; nf < 4; ++nf) sfr[nf] = (f32x4)0.0f;
#pragma unroll
    for (int kk = 0; kk < 2; ++kk) {
#pragma unroll
      for (int nf = 0; nf < 4; ++nf) {
        int row = nf * 16 + (lane & 15);
        int cb = (kk * 64 + ((lane >> 4) << 4)) ^ ((row & 7) << 4);
        short8 ak = *(const short8*)((const char*)Klds + row * 128 + cb);
        sfr[nf] = __builtin_amdgcn_mfma_f32_16x16x32_bf16(ak, aq[kk], sfr[nf], 0, 0, 0);
      }
    }
    if (kb == qb) {
      const int qloc = wave * 16 + (lane & 15);
      const int kg = (lane >> 4) << 2;
#pragma unroll
      for (int nf = 0; nf < 4; ++nf) {
#pragma unroll
        for (int r = 0; r < 4; ++r)
          if (nf * 16 + kg + r > qloc) sfr[nf][r] = -1e30f;
      }
    }
    float pm = -1e30f;
#pragma unroll
    for (int nf = 0; nf < 4; ++nf)
#pragma unroll
      for (int r = 0; r < 4; ++r) pm = fmaxf(pm, sfr[nf][r]);
    pm = fmaxf(pm, __shfl_xor(pm, 16));
    pm = fmaxf(pm, __shfl_xor(pm, 32));
    if (__any(pm > mrun + 8.0f)) {
      float mnew = fmaxf(mrun, pm);
      float corr = exp2f(mrun - mnew);
      mrun = mnew;
      lacc *= corr;
      const int gbase = lane & 48;
#pragma unroll
      for (int r = 0; r < 4; ++r) {
        float cB = __shfl(corr, gbase + ((lane >> 4) << 2) + r);
#pragma unroll
        for (int nf = 0; nf < 4; ++nf) oacc[nf][r] *= cB;
      }
    }
    float ps = 0.0f;
#pragma unroll
    for (int nf = 0; nf < 4; ++nf)
#pragma unroll
      for (int r = 0; r < 4; ++r) {
        float pv = exp2f(sfr[nf][r] - mrun);
        sfr[nf][r] = pv;
        ps += pv;
      }
    ps += __shfl_xor(ps, 16);
    ps += __shfl_xor(ps, 32);
    lacc += ps;
    short8 ap[2];
#pragma unroll
    for (int kk = 0; kk < 2; ++kk) {
      union { uint32_t u[4]; short8 s; } pk;
      pk.u[0] = cvt_pk_bf16(sfr[kk][0], sfr[kk][1]);
      pk.u[1] = cvt_pk_bf16(sfr[kk][2], sfr[kk][3]);
      pk.u[2] = cvt_pk_bf16(sfr[kk + 2][0], sfr[kk + 2][1]);
      pk.u[3] = cvt_pk_bf16(sfr[kk + 2][2], sfr[kk + 2][3]);
      ap[kk] = pk.s;
    }
#pragma unroll
    for (int nf = 0; nf < 4; ++nf) {
#pragma unroll
      for (int kk = 0; kk < 2; ++kk) {
        int row = nf * 16 + (lane & 15);
        int cb = (kk * 64 + ((lane >> 4) << 4)) ^ ((row & 7) << 4);
        short8 bv = *(const short8*)((const char*)Vlds + row * 128 + cb);
        oacc[nf] = __builtin_amdgcn_mfma_f32_16x16x32_bf16(ap[kk], bv, oacc[nf], 0, 0, 0);
      }
    }
    __syncthreads();
  }
  // ---- write bf16 partials ----
  const size_t pb = (size_t)h * NPAIR + p;
#pragma unroll
  for (int nf = 0; nf < 4; ++nf) {
#pragma unroll
    for (int r = 0; r < 4; ++r) {
      int row = wave * 16 + ((lane >> 4) << 2) + r;
      int d = nf * 16 + (lane & 15);
      Opart[(pb * 64 + row) * 64 + d] = f2bf(oacc[nf][r]);
    }
  }
  if (lane < 16) {
    MLpart[pb * 128 + wave * 16 + lane] = mrun;
    MLpart[pb * 128 + 64 + wave * 16 + lane] = lacc;
  }
}

// ---------------- combine partials -> attn bf16 [s][h*64+d] ----------------
__global__ __launch_bounds__(256) void flash_combine(
    const ushort* __restrict__ Opart, const float* __restrict__ MLpart,
    ushort* __restrict__ attn) {
  const int qb = blockIdx.x, h = blockIdx.y;
  const int g = qb >> 3, rr = qb & 7, n = g + 1;
  const int base = qb + 4 * g * (g - 1) + rr * g;
  __shared__ float mS[8][64], lS[8][64];
  const int tid = threadIdx.x;
  for (int i = tid; i < n * 64; i += 256) {
    int part = i >> 6, row = i & 63;
    size_t pb = (size_t)h * NPAIR + base + part;
    mS[part][row] = MLpart[pb * 128 + row];
    lS[part][row] = MLpart[pb * 128 + 64 + row];
  }
  __syncthreads();
  const int d = tid & 63, rg = tid >> 6;
#pragma unroll 4
  for (int k = 0; k < 16; ++k) {
    int row = rg * 16 + k;
    float M = mS[0][row];
    for (int i = 1; i < n; ++i) M = fmaxf(M, mS[i][row]);
    float L = 0.0f, acc = 0.0f;
    for (int i = 0; i < n; ++i) {
      float w = exp2f(mS[i][row] - M);
      L += lS[i][row] * w;
      acc += bf2f(Opart[(((size_t)h * NPAIR + base + i) * 64 + row) * 64 + d]) * w;
    }
    attn[(size_t)(qb * 64 + row) * EDIM + h * 64 + d] = f2bf(acc / L);
  }
}

// ---------------- launcher ----------------
extern "C" void kernel_launch(void* const* d_in, const int* in_sizes, int n_in,
                              void* d_out, int out_size, void* d_ws, size_t ws_size,
                              hipStream_t stream) {
  const float* x     = (const float*)d_in[0];
  const float* Wqa   = (const float*)d_in[2];
  const float* qa_w  = (const float*)d_in[3];
  const float* qa_b  = (const float*)d_in[4];
  const float* Wqb   = (const float*)d_in[5];
  const float* Wkva  = (const float*)d_in[6];
  const float* kva_w = (const float*)d_in[7];
  const float* kva_b = (const float*)d_in[8];
  const float* Wkvb  = (const float*)d_in[9];
  const float* Wo    = (const float*)d_in[10];
  float* out = (float*)d_out;

  char* ws = (char*)d_ws;
  size_t off = 0;
  auto alloc = [&](size_t bytes) {
    char* p = ws + off;
    off += (bytes + 255) & ~(size_t)255;
    return p;
  };
  ushort* xb      = (ushort*)alloc((size_t)SLEN * EDIM * 2);
  ushort* wqkva_b = (ushort*)alloc((size_t)1056 * 1024 * 2);
  ushort* wqb_b   = (ushort*)alloc((size_t)1024 * 512 * 2);
  ushort* wkvb_b  = (ushort*)alloc((size_t)1536 * 512 * 2);
  ushort* wo_b    = (ushort*)alloc((size_t)1024 * 1024 * 2);
  float*  cosT    = (float*)alloc((size_t)SLEN * 16 * 4);
  float*  sinT    = (float*)alloc((size_t)SLEN * 16 * 4);
  ushort* qc_b    = (ushort*)alloc((size_t)SLEN * 512 * 2);
  ushort* qf_b    = (ushort*)alloc((size_t)SLEN * EDIM * 2);
  ushort* ckv_b   = (ushort*)alloc((size_t)SLEN * 512 * 2);
  ushort* kpe_b   = (ushort*)alloc((size_t)SLEN * 32 * 2);
  ushort* kf_b    = (ushort*)alloc((size_t)SLEN * EDIM * 2);
  ushort* vt_b    = (ushort*)alloc((size_t)SLEN * EDIM * 2);
  ushort* attn_b  = (ushort*)alloc((size_t)SLEN * EDIM * 2);
  ushort* qakv_bf = (ushort*)alloc((size_t)SLEN * 1056 * 2);
  float*  MLpart  = (float*)alloc((size_t)NH * NPAIR * 128 * 4);
  // kvdec_bf (12.58MB, dead before flash) aliases Opart (37.75MB)
  char* RB = alloc((size_t)NH * NPAIR * 64 * 64 * 2);
  ushort* kvdec_bf = (ushort*)RB;
  ushort* Opart    = (ushort*)RB;

  // ---- fused casts ----
  CastArgs ca;
  ca.seg[0] = { (const float4*)x,    xb,                               SLEN * EDIM / 4 };
  ca.seg[1] = { (const float4*)Wqa,  wqkva_b,                          512 * 1024 / 4 };
  ca.seg[2] = { (const float4*)Wkva, wqkva_b + (size_t)512 * 1024,     544 * 1024 / 4 };
  ca.seg[3] = { (const float4*)Wqb,  wqb_b,                            1024 * 512 / 4 };
  ca.seg[4] = { (const float4*)Wkvb, wkvb_b,                           1536 * 512 / 4 };
  ca.seg[5] = { (const float4*)Wo,   wo_b,                             1024 * 1024 / 4 };
  ca.total4 = ca.seg[0].n4 + ca.seg[1].n4 + ca.seg[2].n4 + ca.seg[3].n4 + ca.seg[4].n4 + ca.seg[5].n4;
  cast_all<<<dim3(2048), 256, 0, stream>>>(ca);
  rope_table<<<dim3((SLEN * 16 + 255) / 256), 256, 0, stream>>>(cosT, sinT);

  // merged qa+kva projection (bf16 out)
  gemm_bf16k<<<dim3(64, 9), 256, 0, stream>>>(xb, wqkva_b, qakv_bf, SLEN, 1056, 1024);
  ln_both<<<dim3(8192), 256, 0, stream>>>(qakv_bf, qa_w, qa_b, kva_w, kva_b,
                                          qc_b, ckv_b, cosT, sinT, kpe_b);
  // wqb (rope+scale fused -> q_full) + wkvb in one launch
  gemm_dual<<<dim3(64, 20), 256, 0, stream>>>(qc_b, wqb_b, qf_b, ckv_b, wkvb_b, kvdec_bf,
                                              cosT, sinT);
  pack_kv2<<<dim3(64, 16), 256, 0, stream>>>(kvdec_bf, kpe_b, kf_b, vt_b);

  flash_part<<<dim3(NPAIR, 16), 256, 0, stream>>>(qf_b, kf_b, vt_b, Opart, MLpart);
  flash_combine<<<dim3(64, 16), 256, 0, stream>>>(Opart, MLpart, attn_b);
  gemm_f32k<<<dim3(64, 8), 256, 0, stream>>>(attn_b, wo_b, out, SLEN, 1024, 1024);

  (void)in_sizes; (void)n_in; (void)out_size; (void)ws_size;
}